// Round 13
// baseline (40.891 us; speedup 1.0000x reference)
//
#include <hip/hip_runtime.h>
#include <math.h>
#include <stdint.h>

// DbrxRouter on MI355X:
//   logits = x[8192,6144] @ W^T[6144,16]; softmax; top-4; p=1 renorm.
//   Renorm cancels the softmax denominator -> only top-4 logits needed.
//
// Ledger: R7 47.8 (dbuf+__syncthreads) -> R11 42.9 (depth-2 triple-buffer)
// -> R12 40.8 (single counted barrier/step). Per-CU/step service: x 32KB +
// W 16KB x2 blocks = 64KB ~ measured period -> memory-service-bound incl.
// the REDUNDANT per-block W stream (196MB). R13: TPB=512/TOK32/grid=256 =
// 1 block/CU -> W stream halves (98MB), per-step service 48KB (-25%).
// Same triple-buffer single-barrier schedule; 6 vmem ops/issue -> vmcnt(6).

constexpr int H       = 6144;
constexpr int E       = 16;
constexpr int HC      = 256;          // floats per chunk per expert (16KB/buf)
constexpr int NCH     = H / HC;       // 24
constexpr int TPB     = 512;          // 8 waves
constexpr int TOK_PB  = 32;           // 4 tokens per wave, full H per wave
constexpr int T_TOTAL = 8192;

__device__ __forceinline__ void gll16(const float* g, float* l) {
    // global -> LDS direct copy, 16B per lane; dest = wave-uniform base,
    // HW adds lane*16; source is per-lane. Completion tracked by vmcnt.
    __builtin_amdgcn_global_load_lds(
        (const __attribute__((address_space(1))) uint32_t*)g,
        (__attribute__((address_space(3))) uint32_t*)l,
        16, 0, 0);
}

__global__ __launch_bounds__(TPB, 2)
void dbrx_router(const float* __restrict__ x,
                 const float* __restrict__ w,
                 float* __restrict__ out)
{
    __shared__ float wlds[3][E * HC];   // 3 x 16KB W chunk triple-buffer
    __shared__ float lred[8][64];       // [wave][t_loc*16+e] final logits

    const int tid  = threadIdx.x;
    const int wave = tid >> 6;          // 0..7
    const int lane = tid & 63;
    const int tok0 = blockIdx.x * TOK_PB + wave * 4;   // this wave's 4 tokens

    const float* xptr = x + (size_t)tok0 * H + lane * 4;

    float acc[64];                       // [t*16+e], all indices static
    #pragma unroll
    for (int i = 0; i < 64; ++i) acc[i] = 0.f;

    float4 xa[4], xf[4], xg[4];          // x regs for parity 0/1/2 chunks

    // Issue staging for chunk C into LDS buffer B and x reg set XV.
    // 8 waves: round j (0..1) stages expert e = j*8+wave; dest base
    // (j*8+wave)*HC is wave-uniform; 64 lanes x 16B = the full 1KB row.
#define ISSUE(C, B, XV) do {                                           \
        _Pragma("unroll")                                              \
        for (int j = 0; j < 2; ++j)                                    \
            gll16(w + (size_t)(j * 8 + wave) * H + (C) * HC + lane * 4,\
                  &wlds[B][(j * 8 + wave) * HC]);                      \
        _Pragma("unroll")                                              \
        for (int t = 0; t < 4; ++t)                                    \
            XV[t] = *reinterpret_cast<const float4*>(                  \
                xptr + (size_t)t * H + (C) * HC);                      \
    } while (0)

    // Compute one chunk from wlds[B] with x regs XV (all static indices).
#define COMPUTE(B, XV) do {                                            \
        _Pragma("unroll")                                              \
        for (int eb = 0; eb < 4; ++eb) {                               \
            float4 wv[4];                                              \
            _Pragma("unroll")                                          \
            for (int e = 0; e < 4; ++e)                                \
                wv[e] = *reinterpret_cast<const float4*>(              \
                    &wlds[B][(eb * 4 + e) * HC + lane * 4]);           \
            _Pragma("unroll")                                          \
            for (int t = 0; t < 4; ++t)                                \
                _Pragma("unroll")                                      \
                for (int e = 0; e < 4; ++e) {                          \
                    float s = acc[t * 16 + eb * 4 + e];                \
                    s = fmaf(XV[t].x, wv[e].x, s);                     \
                    s = fmaf(XV[t].y, wv[e].y, s);                     \
                    s = fmaf(XV[t].z, wv[e].z, s);                     \
                    s = fmaf(XV[t].w, wv[e].w, s);                     \
                    acc[t * 16 + eb * 4 + e] = s;                      \
                }                                                      \
        }                                                              \
    } while (0)

    // Single barrier per step. vmcnt(6): chunk c's 6 ops retired (only
    // chunk c+1's 6 may remain in flight); lgkmcnt(0): this wave's LDS
    // reads of the to-be-overwritten buffer retired. Barrier makes both
    // globally true before COMPUTE reads / ISSUE overwrites.
#define STEPBAR(NV) do {                                               \
        asm volatile("s_waitcnt vmcnt(" #NV ") lgkmcnt(0)" ::: "memory"); \
        __builtin_amdgcn_s_barrier();                                  \
    } while (0)

    // ---- prologue: chunks 0,1 in flight (12 vmem ops/thread)
    ISSUE(0, 0, xa);
    ISSUE(1, 1, xf);

    // ---- main loop: 3 steps/iter, static parity. Step c: wait+barrier,
    // compute chunk c from buf c%3, issue chunk c+2 into buf (c+2)%3.
    for (int cc = 0; cc < 21; cc += 3) {   // 7 iters: steps c = 0..20
        STEPBAR(6); COMPUTE(0, xa); ISSUE(cc + 2, 2, xg);
        STEPBAR(6); COMPUTE(1, xf); ISSUE(cc + 3, 0, xa);
        STEPBAR(6); COMPUTE(2, xg); ISSUE(cc + 4, 1, xf);
    }
    // ---- tail: steps 21, 22, 23
    STEPBAR(6); COMPUTE(0, xa); ISSUE(23, 2, xg);   // c=21
    STEPBAR(6); COMPUTE(1, xf);                     // c=22
    STEPBAR(0); COMPUTE(2, xg);                     // c=23
#undef ISSUE
#undef COMPUTE
#undef STEPBAR

    // Butterfly reduce-scatter: 64 partials -> lane l holds fully-reduced
    // acc[l] = logits[tok0+(l>>4)][expert l&15]. Fully static indices.
#define RSTEP(S) do {                                                  \
        constexpr int HN = 32 >> (S);                                  \
        const bool hi = (lane & HN) != 0;                              \
        _Pragma("unroll")                                              \
        for (int i = 0; i < HN; ++i) {                                 \
            float send = hi ? acc[i] : acc[i + HN];                    \
            float keep = hi ? acc[i + HN] : acc[i];                    \
            float recv = __shfl_xor(send, HN, 64);                     \
            acc[i] = keep + recv;                                      \
        }                                                              \
    } while (0)
    RSTEP(0); RSTEP(1); RSTEP(2); RSTEP(3); RSTEP(4); RSTEP(5);
#undef RSTEP

    lred[wave][lane] = acc[0];
    __syncthreads();

    // One thread per token: top-4 (strict > == lowest-index tie-break,
    // matching np/jax) + renormalized exp weights. Token = blk*32 + tid.
    if (tid < TOK_PB) {
        float lg[16];
        #pragma unroll
        for (int e = 0; e < 16; ++e)
            lg[e] = lred[tid >> 2][(tid & 3) * 16 + e];

        float topv[4];
        int   topi[4];
        #pragma unroll
        for (int k = 0; k < 4; ++k) {
            float m = lg[0]; int mi = 0;
            #pragma unroll
            for (int e = 1; e < 16; ++e)
                if (lg[e] > m) { m = lg[e]; mi = e; }
            topv[k] = m; topi[k] = mi;
            #pragma unroll
            for (int e = 0; e < 16; ++e)          // static-index mask-out
                if (e == mi) lg[e] = -INFINITY;
        }

        float ex[4]; float sum = 0.f;
        #pragma unroll
        for (int k = 0; k < 4; ++k) { ex[k] = __expf(topv[k] - topv[0]); sum += ex[k]; }
        const float inv = 1.0f / sum;

        const int tok = blockIdx.x * TOK_PB + tid;
        #pragma unroll
        for (int k = 0; k < 4; ++k) {
            out[(size_t)tok * 4 + k] = ex[k] * inv;                          // top_weights
            out[(size_t)T_TOTAL * 4 + (size_t)tok * 4 + k] = (float)topi[k]; // top_experts
        }
    }
}

extern "C" void kernel_launch(void* const* d_in, const int* in_sizes, int n_in,
                              void* d_out, int out_size, void* d_ws, size_t ws_size,
                              hipStream_t stream) {
    const float* x = (const float*)d_in[0];   // hidden_states [4,2048,6144] fp32
    const float* w = (const float*)d_in[1];   // router_weight [16,6144] fp32
    float* out     = (float*)d_out;           // [8192*4 weights][8192*4 expert ids]
    dbrx_router<<<T_TOTAL / TOK_PB, TPB, 0, stream>>>(x, w, out);
}